// Round 12
// baseline (195.949 us; speedup 1.0000x reference)
//
#include <hip/hip_runtime.h>
#include <hip/hip_bf16.h>

#define T_SEQ 2048
#define NBATCH 8
#define EMB 1024
#define HD 128

typedef _Float16 f16_t;
typedef _Float16 f16x8 __attribute__((ext_vector_type(8)));
typedef _Float16 f16x4 __attribute__((ext_vector_type(4)));
typedef float f32x4 __attribute__((ext_vector_type(4)));

// Tiled layouts — every MFMA fragment load is 16B/lane dense:
//  q2/k2 : [tt=row/16][hc=h/8(16)][r16=row%16][8]
//  v2    : [sc=row/8][h(128)][8]
//  w2    : [ntile=n/16(24)][kc8=k/8(128)][r16=n%16][8]
// R11 MODEL (fits R2/R3/R4/R7): qkv wall = cache traffic / ~9 TB/s.
//   traffic = 64MB*(384/n_tile) + 0.75MB*(16384/m_tile).
//   R3 64x128: 388 MB -> 43us. v6 128x192: 224 MB -> pred ~25-32us.
// R12: E-factorization reverted (R10/R11 net-negative vs R9 174.0).
// Attention = R9-verified (attn_out v4 single-barrier, col_stats barrier-free).

// async global->LDS, 16B per lane
__device__ __forceinline__ void g2l(const f16_t* g, f16_t* l) {
    __builtin_amdgcn_global_load_lds(
        (const __attribute__((address_space(1))) unsigned int*)g,
        (__attribute__((address_space(3))) unsigned int*)l, 16, 0, 0);
}

// ---------------------------------------------------------------------------
// Kernel 1: prep — w2 pack + scaled biases (zeroing via memset).
// ---------------------------------------------------------------------------
__global__ __launch_bounds__(256) void prep(
    const float* __restrict__ Wk, const float* __restrict__ bk,
    const float* __restrict__ Wq, const float* __restrict__ bq,
    const float* __restrict__ Wv, const float* __restrict__ bv,
    f16_t* __restrict__ w2, float* __restrict__ biasc) {
    int n = blockIdx.x;
    int t = threadIdx.x;
    const float scale = 0.08838834764831845f;  // HEAD^-0.5
    const float* W; const float* bias; float sc; int col;
    if (n < 128)      { W = Wq; bias = bq; sc = scale; col = n; }
    else if (n < 256) { W = Wk; bias = bk; sc = 1.0f;  col = n - 128; }
    else              { W = Wv; bias = bv; sc = 1.0f;  col = n - 256; }
    if (t < 128) {
        int k0 = t * 8;
        f16x8 v;
        #pragma unroll
        for (int i = 0; i < 8; ++i) v[i] = (f16_t)(W[(size_t)(k0 + i) * HD + col] * sc);
        *(f16x8*)&w2[(size_t)(n >> 4) * 16384 + (size_t)(k0 >> 3) * 128 + (n & 15) * 8] = v;
    }
    if (t == 0) biasc[n] = bias[col] * sc;
}

// ---------------------------------------------------------------------------
// Kernel 2 (v6): 128x192 tiles -> 256 blocks (1/CU). Cache traffic 224 MB
// (vs R3's 388). A staged coalesced (2 rows/thread, 8xfloat4), Xs 36KB dbuf;
// B direct from L2-resident w2 (R0/R7-verified pattern); 1 barrier/chunk
// (R3-verified inner schedule). Wave = 64x96 sub-tile, acc[4][6].
// ---------------------------------------------------------------------------
__global__ __launch_bounds__(256) void qkv_gemm(
    const float* __restrict__ X, const f16_t* __restrict__ w2,
    const float* __restrict__ biasc,
    f16_t* __restrict__ q2, f16_t* __restrict__ k2, f16_t* __restrict__ v2) {
    __shared__ f16_t Xs[2][128 * 72];   // 36 KB

    int bid = blockIdx.x;               // 0..255
    int band = bid >> 1, i = bid & 1;
    int m0 = band * 128, n0 = i * 192;
    int tid = threadIdx.x;
    int lane = tid & 63, w = tid >> 6;
    int quad = lane >> 4, l15 = lane & 15;
    int msub = (w & 1) * 64, nsub = (w >> 1) * 96;

    int srow = tid >> 1;                // 0..127
    int scg  = (tid & 1) * 32;          // f32/f16 col group base

    const float* xrow = X + (size_t)(m0 + srow) * EMB + scg;
    int ntb = (n0 + nsub) >> 4;         // base n-tile (6 tiles per wave)

    f32x4 acc[4][6] = {};
    float4 pf[8];

    auto loadA = [&](int kc) {
        #pragma unroll
        for (int u = 0; u < 8; ++u) pf[u] = *(const float4*)(xrow + kc * 64 + u * 4);
    };
    auto stageA = [&](int buf) {
        #pragma unroll
        for (int p = 0; p < 4; ++p) {
            union { f16_t h[8]; uint4 u4; } pk;
            pk.h[0] = (f16_t)pf[2 * p].x;     pk.h[1] = (f16_t)pf[2 * p].y;
            pk.h[2] = (f16_t)pf[2 * p].z;     pk.h[3] = (f16_t)pf[2 * p].w;
            pk.h[4] = (f16_t)pf[2 * p + 1].x; pk.h[5] = (f16_t)pf[2 * p + 1].y;
            pk.h[6] = (f16_t)pf[2 * p + 1].z; pk.h[7] = (f16_t)pf[2 * p + 1].w;
            *(uint4*)&Xs[buf][srow * 72 + scg + p * 8] = pk.u4;
        }
    };
    auto compute = [&](int kc, int buf) {
        #pragma unroll
        for (int ks = 0; ks < 2; ++ks) {
            f16x8 afr[4];
            #pragma unroll
            for (int mf = 0; mf < 4; ++mf)
                afr[mf] = *(const f16x8*)&Xs[buf][(msub + mf * 16 + l15) * 72 + ks * 32 + quad * 8];
            #pragma unroll
            for (int nf = 0; nf < 6; ++nf) {
                f16x8 bfr = *(const f16x8*)&w2[(size_t)(ntb + nf) * 16384 +
                    (size_t)(kc * 8 + ks * 4 + quad) * 128 + l15 * 8];
                #pragma unroll
                for (int mf = 0; mf < 4; ++mf)
                    acc[mf][nf] = __builtin_amdgcn_mfma_f32_16x16x32_f16(
                        afr[mf], bfr, acc[mf][nf], 0, 0, 0);
            }
        }
    };

    // prologue: fill buffer 0
    loadA(0);
    stageA(0);
    __syncthreads();

    for (int kc = 0; kc < 16; ++kc) {
        int cur = kc & 1;
        if (kc + 1 < 16) loadA(kc + 1);   // issue early; covered by compute
        compute(kc, cur);
        if (kc + 1 < 16) stageA(cur ^ 1); // cvt+ds_write after compute
        __syncthreads();
    }

    // epilogue -> tiled layouts (R3-verified routing)
    #pragma unroll
    for (int nf = 0; nf < 6; ++nf) {
        int ng = n0 + nsub + nf * 16 + l15;
        float bval = biasc[ng];
        #pragma unroll
        for (int mf = 0; mf < 4; ++mf) {
            int rowg = m0 + msub + mf * 16 + quad * 4;
            f32x4 a = acc[mf][nf];
            if (ng < 256) {
                f16_t* dst = (ng < 128) ? q2 : k2;
                int c = ng & 127;
                #pragma unroll
                for (int r = 0; r < 4; ++r) {
                    int row = rowg + r;
                    dst[(size_t)(row >> 4) * 2048 + (c >> 3) * 128 + (row & 15) * 8 + (c & 7)]
                        = (f16_t)(a[r] + bval);
                }
            } else {
                int h = ng - 256;
                f16x4 hv;
                #pragma unroll
                for (int r = 0; r < 4; ++r) hv[r] = (f16_t)(a[r] + bval);
                *(f16x4*)&v2[(size_t)(rowg >> 3) * 1024 + h * 8 + (rowg & 7)] = hv;
            }
        }
    }
}

// ---------------------------------------------------------------------------
// Kernel 3: column sums — R9-verified (barrier-free, direct L2 reads).
// ---------------------------------------------------------------------------
__global__ __launch_bounds__(256, 4) void col_stats(
    const f16_t* __restrict__ q2, const f16_t* __restrict__ k2,
    float* __restrict__ colsum) {
    int bid = blockIdx.x;
    int b = bid & 7;
    int item = 143 - (bid >> 3);
    int cg = 0, slab = 0, cum = 0;
    for (int c = 0; c < 32; ++c) {
        int n = (32 - c + 3) >> 2;
        if (item < cum + n) { cg = c; slab = item - cum; break; }
        cum += n;
    }
    int tc0 = cg + slab * 4, tc1 = min(tc0 + 4, 32);

    int tid = threadIdx.x, lane = tid & 63, w = tid >> 6;
    int quad = lane >> 4, l15 = lane & 15;
    int brow = b * 128;
    size_t base = (size_t)b * T_SEQ;

    f16x8 bfrs[4][4];
    #pragma unroll
    for (int st = 0; st < 4; ++st) {
        const f16_t* kt = k2 + (size_t)(brow + cg * 4 + st) * 2048 + l15 * 8;
        #pragma unroll
        for (int kf = 0; kf < 4; ++kf)
            bfrs[st][kf] = *(const f16x8*)(kt + (kf * 4 + quad) * 128);
    }

    float lacc[4] = {0.f, 0.f, 0.f, 0.f};

    for (int tc = tc0; tc < tc1; ++tc) {
        int tb = tc * 64;
        f16x8 afr[4];
        const f16_t* qt = q2 + (size_t)(brow + tc * 4 + w) * 2048 + l15 * 8;
        #pragma unroll
        for (int kf = 0; kf < 4; ++kf)
            afr[kf] = *(const f16x8*)(qt + (kf * 4 + quad) * 128);
        #pragma unroll
        for (int st = 0; st < 4; ++st) {
            f32x4 s = {};
            #pragma unroll
            for (int kf = 0; kf < 4; ++kf)
                s = __builtin_amdgcn_mfma_f32_16x16x32_f16(afr[kf], bfrs[st][kf], s, 0, 0, 0);
            int scol = cg * 64 + st * 16 + l15;
            #pragma unroll
            for (int r = 0; r < 4; ++r) {
                int t = tb + w * 16 + quad * 4 + r;
                if (t >= scol) lacc[st] += __expf(s[r]);
            }
        }
    }

    #pragma unroll
    for (int st = 0; st < 4; ++st) {
        float v = lacc[st];
        v += __shfl_xor(v, 16, 64);
        v += __shfl_xor(v, 32, 64);
        if (quad == 0) atomicAdd(&colsum[base + cg * 64 + st * 16 + l15], v);
    }
}

// ---------------------------------------------------------------------------
// Kernel 4: output pass — R9-verified v4 (single-barrier pipelined, K/V
// direct to regs, Pl double-buffered, prefetch after barrier).
// ---------------------------------------------------------------------------
__global__ __launch_bounds__(256, 3) void attn_out(
    const f16_t* __restrict__ q2, const f16_t* __restrict__ k2,
    const f16_t* __restrict__ v2, const float* __restrict__ colsum,
    float* __restrict__ out) {
    __shared__ __align__(16) f16_t Pl[2][32 * 72];

    int bid = blockIdx.x;
    int b = bid & 7;
    int item = 159 - (bid >> 3);
    int g = 0, slab = 0, cum = 0;
    for (int gg = 0; gg < 64; ++gg) {
        int n = (((gg >> 1) + 1) + 7) >> 3;
        if (item < cum + n) { g = gg; slab = item - cum; break; }
        cum += n;
    }
    int nch = (g >> 1) + 1;
    int c0 = slab * 8, c1 = min(c0 + 8, nch);
    int trow = g * 32;

    int tid = threadIdx.x, lane = tid & 63, w = tid >> 6;
    int quad = lane >> 4, l15 = lane & 15;
    int brow = b * 128;
    size_t base = (size_t)b * T_SEQ;

    f16x8 qfr[2][4];
    #pragma unroll
    for (int tt = 0; tt < 2; ++tt) {
        const f16_t* qt = q2 + (size_t)(brow + 2 * g + tt) * 2048 + l15 * 8;
        #pragma unroll
        for (int kf = 0; kf < 4; ++kf)
            qfr[tt][kf] = *(const f16x8*)(qt + (kf * 4 + quad) * 128);
    }

    f32x4 o[2][2] = {};

    f16x8 kA[4], kB[4];
    f16x8 vA[2][2], vB[2][2];
    float csA, csB;

    auto loadKVc = [&](int c, f16x8 (&k)[4], f16x8 (&v)[2][2], float& cs) {
        const f16_t* kt = k2 + (size_t)(brow + c * 4 + w) * 2048 + l15 * 8;
        #pragma unroll
        for (int kf = 0; kf < 4; ++kf)
            k[kf] = *(const f16x8*)(kt + (kf * 4 + quad) * 128);
        const f16_t* vt = v2 + ((size_t)(base + c * 64) >> 3) * 1024;
        #pragma unroll
        for (int kf2 = 0; kf2 < 2; ++kf2)
            #pragma unroll
            for (int hh = 0; hh < 2; ++hh)
                v[kf2][hh] = *(const f16x8*)&vt[(kf2 * 4 + quad) * 1024 +
                                                (w * 32 + hh * 16 + l15) * 8];
        cs = colsum[base + c * 64 + w * 16 + l15];
    };
    auto qkt = [&](int c, f16x8 (&k)[4], float cs, int pb) {
        float iv = 1.0f / cs;
        int scol = c * 64 + w * 16 + l15;
        #pragma unroll
        for (int tt = 0; tt < 2; ++tt) {
            f32x4 s = {};
            #pragma unroll
            for (int kf = 0; kf < 4; ++kf)
                s = __builtin_amdgcn_mfma_f32_16x16x32_f16(qfr[tt][kf], k[kf], s, 0, 0, 0);
            #pragma unroll
            for (int r = 0; r < 4; ++r) {
                int t = trow + tt * 16 + quad * 4 + r;
                float pv = (t >= scol) ? __expf(s[r]) * iv : 0.f;
                Pl[pb][(tt * 16 + quad * 4 + r) * 72 + w * 16 + l15] = (f16_t)pv;
            }
        }
    };
    auto pvstep = [&](f16x8 (&v)[2][2], int pb) {
        #pragma unroll
        for (int kf2 = 0; kf2 < 2; ++kf2) {
            f16x8 pa0 = *(const f16x8*)&Pl[pb][(l15) * 72 + kf2 * 32 + quad * 8];
            f16x8 pa1 = *(const f16x8*)&Pl[pb][(16 + l15) * 72 + kf2 * 32 + quad * 8];
            #pragma unroll
            for (int hh = 0; hh < 2; ++hh) {
                o[0][hh] = __builtin_amdgcn_mfma_f32_16x16x32_f16(pa0, v[kf2][hh], o[0][hh], 0, 0, 0);
                o[1][hh] = __builtin_amdgcn_mfma_f32_16x16x32_f16(pa1, v[kf2][hh], o[1][hh], 0, 0, 0);
            }
        }
    };

    int c = c0;
    loadKVc(c, kA, vA, csA);                 // prologue prefetch
    for (; c + 1 < c1; c += 2) {
        qkt(c, kA, csA, 0);
        __syncthreads();                     // Pl[0] visible; kA/vA consumed
        loadKVc(c + 1, kB, vB, csB);         // covered by pvstep below
        pvstep(vA, 0);
        qkt(c + 1, kB, csB, 1);
        __syncthreads();                     // Pl[1] visible
        if (c + 2 < c1) loadKVc(c + 2, kA, vA, csA);
        pvstep(vB, 1);
    }
    if (c < c1) {
        qkt(c, kA, csA, 0);
        __syncthreads();
        pvstep(vA, 0);
    }

    #pragma unroll
    for (int tt = 0; tt < 2; ++tt)
        #pragma unroll
        for (int hh = 0; hh < 2; ++hh)
            #pragma unroll
            for (int r = 0; r < 4; ++r)
                atomicAdd(&out[(base + trow + tt * 16 + quad * 4 + r) * HD + w * 32 + hh * 16 + l15],
                          o[tt][hh][r]);
}

// ---------------------------------------------------------------------------
extern "C" void kernel_launch(void* const* d_in, const int* in_sizes, int n_in,
                              void* d_out, int out_size, void* d_ws, size_t ws_size,
                              hipStream_t stream) {
    const float* X  = (const float*)d_in[0];
    const float* Wk = (const float*)d_in[1];
    const float* bk = (const float*)d_in[2];
    const float* Wq = (const float*)d_in[3];
    const float* bq = (const float*)d_in[4];
    const float* Wv = (const float*)d_in[5];
    const float* bv = (const float*)d_in[6];
    float* out = (float*)d_out;

    char* ws = (char*)d_ws;
    const size_t W2_B    = 24 * 16384 * 2;                   // 768 KiB
    const size_t BIAS_B  = 2048;
    const size_t QKV_B   = (size_t)NBATCH * T_SEQ * HD * 2;  // 4 MiB each
    f16_t* w2     = (f16_t*)ws;
    float* biasc  = (float*)(ws + W2_B);
    f16_t* q2     = (f16_t*)(ws + W2_B + BIAS_B);
    f16_t* k2     = (f16_t*)(ws + W2_B + BIAS_B + QKV_B);
    f16_t* v2     = (f16_t*)(ws + W2_B + BIAS_B + 2 * QKV_B);
    float* colsum = (float*)(ws + W2_B + BIAS_B + 3 * QKV_B);

    // zero out (8MB) + colsum (64KB) via stream-ordered memsets (capture-safe)
    hipMemsetAsync(out, 0, (size_t)NBATCH * T_SEQ * HD * sizeof(float), stream);
    hipMemsetAsync(colsum, 0, (size_t)NBATCH * T_SEQ * sizeof(float), stream);

    prep<<<dim3(384), dim3(256), 0, stream>>>(Wk, bk, Wq, bq, Wv, bv, w2, biasc);
    qkv_gemm<<<dim3(256), dim3(256), 0, stream>>>(X, w2, biasc, q2, k2, v2);
    col_stats<<<dim3(1152), dim3(256), 0, stream>>>(q2, k2, colsum);
    attn_out<<<dim3(1280), dim3(256), 0, stream>>>(q2, k2, v2, colsum, out);
}